// Round 3
// baseline (261.799 us; speedup 1.0000x reference)
//
#include <hip/hip_runtime.h>
#include <stdint.h>

typedef __attribute__((ext_vector_type(4))) float f32x4;
typedef __attribute__((ext_vector_type(8))) short bf16x8;

#define MFMA(a, b, c) __builtin_amdgcn_mfma_f32_16x16x32_bf16(a, b, c, 0, 0, 0)

__device__ __forceinline__ short f2b(float f) {
    uint32_t u = __builtin_bit_cast(uint32_t, f);
    u += 0x7fffu + ((u >> 16) & 1u);
    return (short)(u >> 16);
}

// ---------- cast [Wq;Wk;Wv;Wo] (fp32, each [256][256]) -> Wall bf16 [1024][256]
__global__ void k_cast_w(const float* __restrict__ Wq, const float* __restrict__ Wk,
                         const float* __restrict__ Wv, const float* __restrict__ Wo,
                         short* __restrict__ Wall) {
    int idx = blockIdx.x * 256 + threadIdx.x;   // grid = 1024 blocks
    int row = idx >> 8, col = idx & 255;
    float v;
    if (row < 256)      v = Wq[row * 256 + col];
    else if (row < 512) v = Wk[(row - 256) * 256 + col];
    else if (row < 768) v = Wv[(row - 512) * 256 + col];
    else                v = Wo[(row - 768) * 256 + col];
    Wall[idx] = f2b(v);
}

// ---------- transpose+cast x fp32 [256][2304] -> xt bf16 [2304][256]
__global__ void k_transpose_x(const float* __restrict__ x, short* __restrict__ xt) {
    __shared__ float tile[64][65];
    int pbase = blockIdx.x * 64, cbase = blockIdx.y * 64;  // grid (36,4)
    int tx = threadIdx.x & 63, tq = threadIdx.x >> 6;
    #pragma unroll
    for (int r = 0; r < 16; r++) {
        int row = tq * 16 + r;
        tile[row][tx] = x[(cbase + row) * 2304 + pbase + tx];
    }
    __syncthreads();
    #pragma unroll
    for (int r = 0; r < 16; r++) {
        int prow = tq * 16 + r;
        xt[(pbase + prow) * 256 + cbase + tx] = f2b(tile[tx][prow]);
    }
}

// ---------- QKV projection: C[768][2304] = Wall[0:768] @ x ; scatter to Qf/Kf/Vt
// Qf[n][64] bf16 (pre-scaled 1/8), Kf[n][64] bf16, Vt[64][9216] bf16, n = p*4+h
__global__ __launch_bounds__(256) void k_gemm_qkv(
    const short* __restrict__ Wall, const short* __restrict__ xt,
    const float* __restrict__ bq, const float* __restrict__ bk, const float* __restrict__ bv,
    short* __restrict__ Qf, short* __restrict__ Kf, short* __restrict__ Vt) {
    int t = threadIdx.x, wave = t >> 6, lane = t & 63, lr = lane & 15, lg = lane >> 4;
    int obase = blockIdx.x * 64 + wave * 16;   // grid.x = 12
    int pbase = blockIdx.y * 64;               // grid.y = 36
    const short* arow  = Wall + (obase + lr) * 256 + lg * 8;
    const short* brow0 = xt + (pbase +  0 + lr) * 256 + lg * 8;
    const short* brow1 = xt + (pbase + 16 + lr) * 256 + lg * 8;
    const short* brow2 = xt + (pbase + 32 + lr) * 256 + lg * 8;
    const short* brow3 = xt + (pbase + 48 + lr) * 256 + lg * 8;
    f32x4 acc0 = {0,0,0,0}, acc1 = {0,0,0,0}, acc2 = {0,0,0,0}, acc3 = {0,0,0,0};
    #pragma unroll
    for (int ks = 0; ks < 8; ks++) {
        bf16x8 a = *(const bf16x8*)(arow + ks * 32);
        acc0 = MFMA(a, *(const bf16x8*)(brow0 + ks * 32), acc0);
        acc1 = MFMA(a, *(const bf16x8*)(brow1 + ks * 32), acc1);
        acc2 = MFMA(a, *(const bf16x8*)(brow2 + ks * 32), acc2);
        acc3 = MFMA(a, *(const bf16x8*)(brow3 + ks * 32), acc3);
    }
    int w_idx = obase >> 8;  // 0=q 1=k 2=v, uniform per block
    const float* bias = (w_idx == 0) ? bq : (w_idx == 1) ? bk : bv;
    f32x4 accs[4] = {acc0, acc1, acc2, acc3};
    #pragma unroll
    for (int i = 0; i < 4; i++) {
        int o = obase + 4 * lg + i;
        int oo = o & 255;
        float b = bias[oo];
        int h = oo >> 6, d = oo & 63;
        #pragma unroll
        for (int ct = 0; ct < 4; ct++) {
            int p = pbase + ct * 16 + lr;
            float val = accs[ct][i] + b;
            int n = p * 4 + h;
            if (w_idx == 0)      Qf[n * 64 + d] = f2b(val * 0.125f);
            else if (w_idx == 1) Kf[n * 64 + d] = f2b(val);
            else                 Vt[d * 9216 + n] = f2b(val);
        }
    }
}

// ---------- flash attention: N=9216, d=64. Grid (576 qblocks, 4 kvblocks).
// Block = 8 waves x 512 thr; owns 16 queries x 2304 keys; wave w handles keys
// [(kb*8+w)*288, +288) in 9 tiles of 32. launch_bounds(512,4) -> 128 VGPR so the
// whole working set (Q frags, K cur+next prefetch, V, acc) lives in registers.
// Swapped QK^T (mfma(K,Q) = S^T, permuted K rows) => S^T acc regs are exactly the
// B-fragment for PV. Denominator via ones-MFMA (no sum shfls); max-reduce via 3
// parallel shfl_xor.
__global__ __launch_bounds__(512, 4) void k_attn(
    const short* __restrict__ Qf, const short* __restrict__ Kf,
    const short* __restrict__ Vt,
    float* __restrict__ pm, float* __restrict__ ps, float* __restrict__ pacc) {
    __shared__ float lds_m[8][16];
    __shared__ float lds_s[8][16];
    __shared__ float lds_acc[64][16];
    int t = threadIdx.x, wave = t >> 6, lane = t & 63, lr = lane & 15, lg = lane >> 4;
    int qbase = blockIdx.x * 16;   // grid.x = 576
    int kb = blockIdx.y;           // grid.y = 4
    #pragma unroll
    for (int r = 0; r < 2; r++) ((float*)lds_acc)[t + 512 * r] = 0.f;

    const short* qrow = Qf + (qbase + lr) * 64 + lg * 8;
    bf16x8 qA0 = *(const bf16x8*)(qrow);
    bf16x8 qA1 = *(const bf16x8*)(qrow + 32);

    bf16x8 ones;
    #pragma unroll
    for (int i = 0; i < 8; i++) ones[i] = (short)0x3F80;   // bf16 1.0

    float mA = -1e30f;
    f32x4 zv = {0,0,0,0};
    f32x4 acc[4];
    #pragma unroll
    for (int i = 0; i < 4; i++) acc[i] = zv;
    f32x4 sacc = zv;

    int perm = (lr & 3) + 8 * (lr >> 2);   // K-row permutation: st regs -> B-frag layout
    int jstart = (kb * 8 + wave) * 288;

    const short* kp0 = Kf + (jstart + perm) * 64 + lg * 8;
    bf16x8 kc0 = *(const bf16x8*)(kp0);
    bf16x8 kc1 = *(const bf16x8*)(kp0 + 32);
    bf16x8 kc2 = *(const bf16x8*)(kp0 + 256);
    bf16x8 kc3 = *(const bf16x8*)(kp0 + 256 + 32);

    for (int it = 0; it < 9; it++) {
        int jb = jstart + it * 32;
        // V for current tile (needed only after softmax -> latency covered)
        const short* vp = Vt + lr * 9216 + jb + lg * 8;
        bf16x8 v0 = *(const bf16x8*)(vp);
        bf16x8 v1 = *(const bf16x8*)(vp + 16 * 9216);
        bf16x8 v2 = *(const bf16x8*)(vp + 32 * 9216);
        bf16x8 v3 = *(const bf16x8*)(vp + 48 * 9216);
        // prefetch next K tile into regs (wrap on last iter; discarded)
        int jn = (it < 8) ? jb + 32 : jstart;
        const short* knp = Kf + (jn + perm) * 64 + lg * 8;
        bf16x8 kn0 = *(const bf16x8*)(knp);
        bf16x8 kn1 = *(const bf16x8*)(knp + 32);
        bf16x8 kn2 = *(const bf16x8*)(knp + 256);
        bf16x8 kn3 = *(const bf16x8*)(knp + 256 + 32);

        // QK^T (S^T): rows = keys (perm'd), cols = queries
        f32x4 st0 = MFMA(kc0, qA0, zv); st0 = MFMA(kc1, qA1, st0);
        f32x4 st1 = MFMA(kc2, qA0, zv); st1 = MFMA(kc3, qA1, st1);

        // online softmax: max over 32 keys for q = qbase+lr
        float tm = fmaxf(fmaxf(fmaxf(st0[0], st0[1]), fmaxf(st0[2], st0[3])),
                         fmaxf(fmaxf(st1[0], st1[1]), fmaxf(st1[2], st1[3])));
        float ta = __shfl_xor(tm, 16);
        float tb = __shfl_xor(tm, 32);
        float tc = __shfl_xor(tm, 48);
        tm = fmaxf(fmaxf(tm, ta), fmaxf(tb, tc));
        float mn = fmaxf(mA, tm);
        float sc = __expf(mA - mn);
        mA = mn;
        bf16x8 pb;
        pb[0] = f2b(__expf(st0[0] - mn)); pb[1] = f2b(__expf(st0[1] - mn));
        pb[2] = f2b(__expf(st0[2] - mn)); pb[3] = f2b(__expf(st0[3] - mn));
        pb[4] = f2b(__expf(st1[0] - mn)); pb[5] = f2b(__expf(st1[1] - mn));
        pb[6] = f2b(__expf(st1[2] - mn)); pb[7] = f2b(__expf(st1[3] - mn));

        // PV + denominator (ones-MFMA); rescale accumulators by sc
        acc[0] = MFMA(v0, pb, acc[0] * sc);
        acc[1] = MFMA(v1, pb, acc[1] * sc);
        acc[2] = MFMA(v2, pb, acc[2] * sc);
        acc[3] = MFMA(v3, pb, acc[3] * sc);
        sacc   = MFMA(ones, pb, sacc * sc);

        kc0 = kn0; kc1 = kn1; kc2 = kn2; kc3 = kn3;
    }

    // ---- combine the 8 waves within the block
    if (lane < 16) {           // lg==0: sacc[0] = s[q=lr]
        lds_m[wave][lr] = mA;
        lds_s[wave][lr] = sacc[0];
    }
    __syncthreads();
    float mg = lds_m[0][lr];
    #pragma unroll
    for (int w = 1; w < 8; w++) mg = fmaxf(mg, lds_m[w][lr]);
    float fA = __expf(mA - mg);
    #pragma unroll
    for (int dvt = 0; dvt < 4; dvt++) {
        #pragma unroll
        for (int i = 0; i < 4; i++)
            atomicAdd(&lds_acc[dvt * 16 + 4 * lg + i][lr], acc[dvt][i] * fA);
    }
    __syncthreads();
    int pidx = kb * 576 + blockIdx.x;
    if (t < 16) {
        int q = t;
        float mgq = lds_m[0][q];
        #pragma unroll
        for (int w = 1; w < 8; w++) mgq = fmaxf(mgq, lds_m[w][q]);
        float S = 0.f;
        #pragma unroll
        for (int w = 0; w < 8; w++) S += lds_s[w][q] * __expf(lds_m[w][q] - mgq);
        pm[pidx * 16 + q] = mgq;
        ps[pidx * 16 + q] = S;
    }
    #pragma unroll
    for (int r = 0; r < 2; r++) {
        int idx = t + 512 * r;
        pacc[pidx * 1024 + idx] = ((float*)lds_acc)[idx];
    }
}

// ---------- combine 4 KV-split partials -> Of bf16 [2304][256]
__global__ __launch_bounds__(256) void k_attn_combine(
    const float* __restrict__ pm, const float* __restrict__ ps,
    const float* __restrict__ pacc, short* __restrict__ Of) {
    int qb = blockIdx.x, t = threadIdx.x;   // grid = 576
    #pragma unroll
    for (int r = 0; r < 4; r++) {
        int idx = t + 256 * r;              // 0..1023
        int dv = idx >> 4, q = idx & 15;
        float m0 = pm[(0 * 576 + qb) * 16 + q], m1 = pm[(1 * 576 + qb) * 16 + q];
        float m2 = pm[(2 * 576 + qb) * 16 + q], m3 = pm[(3 * 576 + qb) * 16 + q];
        float mg = fmaxf(fmaxf(m0, m1), fmaxf(m2, m3));
        float e0 = __expf(m0 - mg), e1 = __expf(m1 - mg);
        float e2 = __expf(m2 - mg), e3 = __expf(m3 - mg);
        float S = ps[(0 * 576 + qb) * 16 + q] * e0 + ps[(1 * 576 + qb) * 16 + q] * e1
                + ps[(2 * 576 + qb) * 16 + q] * e2 + ps[(3 * 576 + qb) * 16 + q] * e3;
        float O = pacc[(0 * 576 + qb) * 1024 + idx] * e0
                + pacc[(1 * 576 + qb) * 1024 + idx] * e1
                + pacc[(2 * 576 + qb) * 1024 + idx] * e2
                + pacc[(3 * 576 + qb) * 1024 + idx] * e3;
        int n = qb * 16 + q, p = n >> 2, hh = n & 3;
        Of[p * 256 + hh * 64 + dv] = f2b(O / S);
    }
}

// ---------- output projection: out[256][2304] = Wo @ Of^T + bo (fp32 out, NCHW)
__global__ __launch_bounds__(256) void k_gemm_out(
    const short* __restrict__ Wo_bf, const short* __restrict__ Of,
    const float* __restrict__ bo, float* __restrict__ out) {
    int t = threadIdx.x, wave = t >> 6, lane = t & 63, lr = lane & 15, lg = lane >> 4;
    int obase = blockIdx.x * 64 + wave * 16;   // grid.x = 4
    int pbase = blockIdx.y * 64;               // grid.y = 36
    const short* arow  = Wo_bf + (obase + lr) * 256 + lg * 8;
    const short* brow0 = Of + (pbase +  0 + lr) * 256 + lg * 8;
    const short* brow1 = Of + (pbase + 16 + lr) * 256 + lg * 8;
    const short* brow2 = Of + (pbase + 32 + lr) * 256 + lg * 8;
    const short* brow3 = Of + (pbase + 48 + lr) * 256 + lg * 8;
    f32x4 acc0 = {0,0,0,0}, acc1 = {0,0,0,0}, acc2 = {0,0,0,0}, acc3 = {0,0,0,0};
    #pragma unroll
    for (int ks = 0; ks < 8; ks++) {
        bf16x8 a = *(const bf16x8*)(arow + ks * 32);
        acc0 = MFMA(a, *(const bf16x8*)(brow0 + ks * 32), acc0);
        acc1 = MFMA(a, *(const bf16x8*)(brow1 + ks * 32), acc1);
        acc2 = MFMA(a, *(const bf16x8*)(brow2 + ks * 32), acc2);
        acc3 = MFMA(a, *(const bf16x8*)(brow3 + ks * 32), acc3);
    }
    f32x4 accs[4] = {acc0, acc1, acc2, acc3};
    #pragma unroll
    for (int i = 0; i < 4; i++) {
        int o = obase + 4 * lg + i;
        float b = bo[o];
        #pragma unroll
        for (int ct = 0; ct < 4; ct++) {
            int p = pbase + ct * 16 + lr;
            out[o * 2304 + p] = accs[ct][i] + b;
        }
    }
}

extern "C" void kernel_launch(void* const* d_in, const int* in_sizes, int n_in,
                              void* d_out, int out_size, void* d_ws, size_t ws_size,
                              hipStream_t stream) {
    const float* x  = (const float*)d_in[0];
    const float* Wq = (const float*)d_in[1];
    const float* bq = (const float*)d_in[2];
    const float* Wk = (const float*)d_in[3];
    const float* bk = (const float*)d_in[4];
    const float* Wv = (const float*)d_in[5];
    const float* bv = (const float*)d_in[6];
    const float* Wo = (const float*)d_in[7];
    const float* bo = (const float*)d_in[8];

    char* ws = (char*)d_ws;
    short* Wall = (short*)(ws);                     // 1024*256*2 = 524288 B
    short* xt   = (short*)(ws + 524288);            // 2304*256*2 = 1179648 B
    short* Qf   = (short*)(ws + 1703936);           // 9216*64*2
    short* Kf   = (short*)(ws + 2883584);           // 9216*64*2
    short* Vt   = (short*)(ws + 4063232);           // 64*9216*2
    short* Of   = (short*)(ws + 5242880);           // 2304*256*2
    float* pm   = (float*)(ws + 6422528);           // 4*576*16*4 = 147456
    float* ps   = (float*)(ws + 6569984);           // 147456
    float* pacc = (float*)(ws + 6717440);           // 4*576*1024*4 = 9437184 (end ~16.2MB)
    float* out  = (float*)d_out;

    k_cast_w<<<1024, 256, 0, stream>>>(Wq, Wk, Wv, Wo, Wall);
    k_transpose_x<<<dim3(36, 4), 256, 0, stream>>>(x, xt);
    k_gemm_qkv<<<dim3(12, 36), 256, 0, stream>>>(Wall, xt, bq, bk, bv, Qf, Kf, Vt);
    k_attn<<<dim3(576, 4), 512, 0, stream>>>(Qf, Kf, Vt, pm, ps, pacc);
    k_attn_combine<<<576, 256, 0, stream>>>(pm, ps, pacc, Of);
    k_gemm_out<<<dim3(4, 36), 256, 0, stream>>>(Wall + 768 * 256, Of, bo, out);
}

// Round 4
// 223.666 us; speedup vs baseline: 1.1705x; 1.1705x over previous
//
#include <hip/hip_runtime.h>
#include <stdint.h>

typedef __attribute__((ext_vector_type(4))) float f32x4;
typedef __attribute__((ext_vector_type(8))) short bf16x8;

#define MFMA(a, b, c) __builtin_amdgcn_mfma_f32_16x16x32_bf16(a, b, c, 0, 0, 0)

__device__ __forceinline__ short f2b(float f) {
    uint32_t u = __builtin_bit_cast(uint32_t, f);
    u += 0x7fffu + ((u >> 16) & 1u);
    return (short)(u >> 16);
}

// ---------- cast [Wq;Wk;Wv;Wo] (fp32, each [256][256]) -> Wall bf16 [1024][256]
__global__ void k_cast_w(const float* __restrict__ Wq, const float* __restrict__ Wk,
                         const float* __restrict__ Wv, const float* __restrict__ Wo,
                         short* __restrict__ Wall) {
    int idx = blockIdx.x * 256 + threadIdx.x;   // grid = 1024 blocks
    int row = idx >> 8, col = idx & 255;
    float v;
    if (row < 256)      v = Wq[row * 256 + col];
    else if (row < 512) v = Wk[(row - 256) * 256 + col];
    else if (row < 768) v = Wv[(row - 512) * 256 + col];
    else                v = Wo[(row - 768) * 256 + col];
    Wall[idx] = f2b(v);
}

// ---------- transpose+cast x fp32 [256][2304] -> xt bf16 [2304][256]
__global__ void k_transpose_x(const float* __restrict__ x, short* __restrict__ xt) {
    __shared__ float tile[64][65];
    int pbase = blockIdx.x * 64, cbase = blockIdx.y * 64;  // grid (36,4)
    int tx = threadIdx.x & 63, tq = threadIdx.x >> 6;
    #pragma unroll
    for (int r = 0; r < 16; r++) {
        int row = tq * 16 + r;
        tile[row][tx] = x[(cbase + row) * 2304 + pbase + tx];
    }
    __syncthreads();
    #pragma unroll
    for (int r = 0; r < 16; r++) {
        int prow = tq * 16 + r;
        xt[(pbase + prow) * 256 + cbase + tx] = f2b(tile[tx][prow]);
    }
}

// ---------- QKV projection: C[768][2304] = Wall[0:768] @ x ; scatter to Qf/Kf/Vt
// Qf[n][64] bf16 (pre-scaled 1/8), Kf[n][64] bf16, Vt[64][9216] bf16, n = p*4+h
__global__ __launch_bounds__(256) void k_gemm_qkv(
    const short* __restrict__ Wall, const short* __restrict__ xt,
    const float* __restrict__ bq, const float* __restrict__ bk, const float* __restrict__ bv,
    short* __restrict__ Qf, short* __restrict__ Kf, short* __restrict__ Vt) {
    int t = threadIdx.x, wave = t >> 6, lane = t & 63, lr = lane & 15, lg = lane >> 4;
    int obase = blockIdx.x * 64 + wave * 16;   // grid.x = 12
    int pbase = blockIdx.y * 64;               // grid.y = 36
    const short* arow  = Wall + (obase + lr) * 256 + lg * 8;
    const short* brow0 = xt + (pbase +  0 + lr) * 256 + lg * 8;
    const short* brow1 = xt + (pbase + 16 + lr) * 256 + lg * 8;
    const short* brow2 = xt + (pbase + 32 + lr) * 256 + lg * 8;
    const short* brow3 = xt + (pbase + 48 + lr) * 256 + lg * 8;
    f32x4 acc0 = {0,0,0,0}, acc1 = {0,0,0,0}, acc2 = {0,0,0,0}, acc3 = {0,0,0,0};
    #pragma unroll
    for (int ks = 0; ks < 8; ks++) {
        bf16x8 a = *(const bf16x8*)(arow + ks * 32);
        acc0 = MFMA(a, *(const bf16x8*)(brow0 + ks * 32), acc0);
        acc1 = MFMA(a, *(const bf16x8*)(brow1 + ks * 32), acc1);
        acc2 = MFMA(a, *(const bf16x8*)(brow2 + ks * 32), acc2);
        acc3 = MFMA(a, *(const bf16x8*)(brow3 + ks * 32), acc3);
    }
    int w_idx = obase >> 8;  // 0=q 1=k 2=v, uniform per block
    const float* bias = (w_idx == 0) ? bq : (w_idx == 1) ? bk : bv;
    f32x4 accs[4] = {acc0, acc1, acc2, acc3};
    #pragma unroll
    for (int i = 0; i < 4; i++) {
        int o = obase + 4 * lg + i;
        int oo = o & 255;
        float b = bias[oo];
        int h = oo >> 6, d = oo & 63;
        #pragma unroll
        for (int ct = 0; ct < 4; ct++) {
            int p = pbase + ct * 16 + lr;
            float val = accs[ct][i] + b;
            int n = p * 4 + h;
            if (w_idx == 0)      Qf[n * 64 + d] = f2b(val * 0.125f);
            else if (w_idx == 1) Kf[n * 64 + d] = f2b(val);
            else                 Vt[d * 9216 + n] = f2b(val);
        }
    }
}

// ---------- flash attention: N=9216, d=64. Grid (288 qblocks, 4 kvblocks).
// Block = 8 waves x 512 thr; owns 32 queries x 2304 keys (= 72 tiles of 32).
// DE-LOCKSTEP: wave w at iter it reads tile (8*it + w + qb) % 72, so no two
// q-blocks stream the same K/V cache lines at the same instant (hot-line fix).
// Swapped QK^T (mfma(K,Q)=S^T, permuted K rows) => S^T regs are the PV B-frag.
// Denominator via ones-MFMA (no sum shfls); max-reduce via 3 parallel shfl_xor.
__global__ __launch_bounds__(512, 4) void k_attn(
    const short* __restrict__ Qf, const short* __restrict__ Kf,
    const short* __restrict__ Vt,
    float* __restrict__ pm, float* __restrict__ ps, float* __restrict__ pacc) {
    __shared__ float lds_m[8][32];
    __shared__ float lds_s[8][32];
    __shared__ float lds_acc[64][32];
    int t = threadIdx.x, wave = t >> 6, lane = t & 63, lr = lane & 15, lg = lane >> 4;
    int qb = blockIdx.x;           // grid.x = 288
    int qbase = qb * 32;
    int kb = blockIdx.y;           // grid.y = 4
    #pragma unroll
    for (int r = 0; r < 4; r++) ((float*)lds_acc)[t + 512 * r] = 0.f;

    const short* qrowA = Qf + (qbase + lr) * 64 + lg * 8;
    const short* qrowB = qrowA + 16 * 64;
    bf16x8 qA0 = *(const bf16x8*)(qrowA);
    bf16x8 qA1 = *(const bf16x8*)(qrowA + 32);
    bf16x8 qB0 = *(const bf16x8*)(qrowB);
    bf16x8 qB1 = *(const bf16x8*)(qrowB + 32);

    bf16x8 ones;
    #pragma unroll
    for (int i = 0; i < 8; i++) ones[i] = (short)0x3F80;   // bf16 1.0

    float mA = -1e30f, mB = -1e30f;
    f32x4 zv = {0,0,0,0};
    f32x4 accA[4], accB[4];
    #pragma unroll
    for (int i = 0; i < 4; i++) { accA[i] = zv; accB[i] = zv; }
    f32x4 saccA = zv, saccB = zv;

    int perm = (lr & 3) + 8 * (lr >> 2);   // K-row permutation: st regs -> B-frag layout
    int kbase = kb * 2304;
    int phase0 = wave + qb;

    for (int it = 0; it < 9; it++) {
        int tt = (8 * it + phase0) % 72;
        int jb = kbase + tt * 32;
        // issue all 8 loads up front; QK waits only on K (vmcnt), V hides under softmax
        const short* kp = Kf + (jb + perm) * 64 + lg * 8;
        bf16x8 k00 = *(const bf16x8*)(kp);
        bf16x8 k01 = *(const bf16x8*)(kp + 32);
        bf16x8 k10 = *(const bf16x8*)(kp + 256);       // +4 rows
        bf16x8 k11 = *(const bf16x8*)(kp + 256 + 32);
        const short* vp = Vt + lr * 9216 + jb + lg * 8;
        bf16x8 v0 = *(const bf16x8*)(vp);
        bf16x8 v1 = *(const bf16x8*)(vp + 16 * 9216);
        bf16x8 v2 = *(const bf16x8*)(vp + 32 * 9216);
        bf16x8 v3 = *(const bf16x8*)(vp + 48 * 9216);

        // QK^T (S^T): rows = keys (perm'd), cols = queries
        f32x4 st00 = MFMA(k00, qA0, zv); st00 = MFMA(k01, qA1, st00);
        f32x4 st10 = MFMA(k10, qA0, zv); st10 = MFMA(k11, qA1, st10);
        f32x4 st01 = MFMA(k00, qB0, zv); st01 = MFMA(k01, qB1, st01);
        f32x4 st11 = MFMA(k10, qB0, zv); st11 = MFMA(k11, qB1, st11);

        // ---- online softmax, q-subtile A (q = qbase+lr)
        float tm = fmaxf(fmaxf(fmaxf(st00[0], st00[1]), fmaxf(st00[2], st00[3])),
                         fmaxf(fmaxf(st10[0], st10[1]), fmaxf(st10[2], st10[3])));
        float ta = __shfl_xor(tm, 16);
        float tb = __shfl_xor(tm, 32);
        float tc = __shfl_xor(tm, 48);
        tm = fmaxf(fmaxf(tm, ta), fmaxf(tb, tc));
        float mnA = fmaxf(mA, tm);
        float scA = __expf(mA - mnA);
        mA = mnA;
        bf16x8 pbA;
        pbA[0] = f2b(__expf(st00[0] - mnA)); pbA[1] = f2b(__expf(st00[1] - mnA));
        pbA[2] = f2b(__expf(st00[2] - mnA)); pbA[3] = f2b(__expf(st00[3] - mnA));
        pbA[4] = f2b(__expf(st10[0] - mnA)); pbA[5] = f2b(__expf(st10[1] - mnA));
        pbA[6] = f2b(__expf(st10[2] - mnA)); pbA[7] = f2b(__expf(st10[3] - mnA));

        // ---- q-subtile B (q = qbase+16+lr)
        tm = fmaxf(fmaxf(fmaxf(st01[0], st01[1]), fmaxf(st01[2], st01[3])),
                   fmaxf(fmaxf(st11[0], st11[1]), fmaxf(st11[2], st11[3])));
        ta = __shfl_xor(tm, 16);
        tb = __shfl_xor(tm, 32);
        tc = __shfl_xor(tm, 48);
        tm = fmaxf(fmaxf(tm, ta), fmaxf(tb, tc));
        float mnB = fmaxf(mB, tm);
        float scB = __expf(mB - mnB);
        mB = mnB;
        bf16x8 pbB;
        pbB[0] = f2b(__expf(st01[0] - mnB)); pbB[1] = f2b(__expf(st01[1] - mnB));
        pbB[2] = f2b(__expf(st01[2] - mnB)); pbB[3] = f2b(__expf(st01[3] - mnB));
        pbB[4] = f2b(__expf(st11[0] - mnB)); pbB[5] = f2b(__expf(st11[1] - mnB));
        pbB[6] = f2b(__expf(st11[2] - mnB)); pbB[7] = f2b(__expf(st11[3] - mnB));

        // ---- PV + denominators (ones-MFMA); rescale accumulators
        accA[0] = MFMA(v0, pbA, accA[0] * scA);
        accA[1] = MFMA(v1, pbA, accA[1] * scA);
        accA[2] = MFMA(v2, pbA, accA[2] * scA);
        accA[3] = MFMA(v3, pbA, accA[3] * scA);
        saccA   = MFMA(ones, pbA, saccA * scA);
        accB[0] = MFMA(v0, pbB, accB[0] * scB);
        accB[1] = MFMA(v1, pbB, accB[1] * scB);
        accB[2] = MFMA(v2, pbB, accB[2] * scB);
        accB[3] = MFMA(v3, pbB, accB[3] * scB);
        saccB   = MFMA(ones, pbB, saccB * scB);
    }

    // ---- combine the 8 waves within the block
    if (lane < 16) {              // lg==0: sacc[0] = s[q]
        lds_m[wave][lane] = mA;      lds_s[wave][lane] = saccA[0];
        lds_m[wave][16 + lane] = mB; lds_s[wave][16 + lane] = saccB[0];
    }
    __syncthreads();
    float mgA = lds_m[0][lr], mgB = lds_m[0][16 + lr];
    #pragma unroll
    for (int w = 1; w < 8; w++) {
        mgA = fmaxf(mgA, lds_m[w][lr]);
        mgB = fmaxf(mgB, lds_m[w][16 + lr]);
    }
    float fA = __expf(mA - mgA), fB = __expf(mB - mgB);
    #pragma unroll
    for (int dvt = 0; dvt < 4; dvt++) {
        #pragma unroll
        for (int i = 0; i < 4; i++) {
            atomicAdd(&lds_acc[dvt * 16 + 4 * lg + i][lr],      accA[dvt][i] * fA);
            atomicAdd(&lds_acc[dvt * 16 + 4 * lg + i][16 + lr], accB[dvt][i] * fB);
        }
    }
    __syncthreads();
    int pidx = kb * 288 + qb;
    if (t < 32) {
        int q = t;
        float mg = lds_m[0][q];
        #pragma unroll
        for (int w = 1; w < 8; w++) mg = fmaxf(mg, lds_m[w][q]);
        float S = 0.f;
        #pragma unroll
        for (int w = 0; w < 8; w++) S += lds_s[w][q] * __expf(lds_m[w][q] - mg);
        pm[pidx * 32 + q] = mg;
        ps[pidx * 32 + q] = S;
    }
    #pragma unroll
    for (int r = 0; r < 4; r++) {
        int idx = t + 512 * r;
        pacc[pidx * 2048 + idx] = ((float*)lds_acc)[idx];
    }
}

// ---------- combine 4 KV-split partials -> Of bf16 [2304][256]
__global__ __launch_bounds__(256) void k_attn_combine(
    const float* __restrict__ pm, const float* __restrict__ ps,
    const float* __restrict__ pacc, short* __restrict__ Of) {
    int qb = blockIdx.x, t = threadIdx.x;   // grid = 288
    #pragma unroll
    for (int r = 0; r < 8; r++) {
        int idx = t + 256 * r;              // 0..2047
        int dv = idx >> 5, q = idx & 31;
        float m0 = pm[(0 * 288 + qb) * 32 + q], m1 = pm[(1 * 288 + qb) * 32 + q];
        float m2 = pm[(2 * 288 + qb) * 32 + q], m3 = pm[(3 * 288 + qb) * 32 + q];
        float mg = fmaxf(fmaxf(m0, m1), fmaxf(m2, m3));
        float e0 = __expf(m0 - mg), e1 = __expf(m1 - mg);
        float e2 = __expf(m2 - mg), e3 = __expf(m3 - mg);
        float S = ps[(0 * 288 + qb) * 32 + q] * e0 + ps[(1 * 288 + qb) * 32 + q] * e1
                + ps[(2 * 288 + qb) * 32 + q] * e2 + ps[(3 * 288 + qb) * 32 + q] * e3;
        float O = pacc[(0 * 288 + qb) * 2048 + idx] * e0
                + pacc[(1 * 288 + qb) * 2048 + idx] * e1
                + pacc[(2 * 288 + qb) * 2048 + idx] * e2
                + pacc[(3 * 288 + qb) * 2048 + idx] * e3;
        int n = qb * 32 + q, p = n >> 2, hh = n & 3;
        Of[p * 256 + hh * 64 + dv] = f2b(O / S);
    }
}

// ---------- output projection: out[256][2304] = Wo @ Of^T + bo (fp32 out, NCHW)
__global__ __launch_bounds__(256) void k_gemm_out(
    const short* __restrict__ Wo_bf, const short* __restrict__ Of,
    const float* __restrict__ bo, float* __restrict__ out) {
    int t = threadIdx.x, wave = t >> 6, lane = t & 63, lr = lane & 15, lg = lane >> 4;
    int obase = blockIdx.x * 64 + wave * 16;   // grid.x = 4
    int pbase = blockIdx.y * 64;               // grid.y = 36
    const short* arow  = Wo_bf + (obase + lr) * 256 + lg * 8;
    const short* brow0 = Of + (pbase +  0 + lr) * 256 + lg * 8;
    const short* brow1 = Of + (pbase + 16 + lr) * 256 + lg * 8;
    const short* brow2 = Of + (pbase + 32 + lr) * 256 + lg * 8;
    const short* brow3 = Of + (pbase + 48 + lr) * 256 + lg * 8;
    f32x4 acc0 = {0,0,0,0}, acc1 = {0,0,0,0}, acc2 = {0,0,0,0}, acc3 = {0,0,0,0};
    #pragma unroll
    for (int ks = 0; ks < 8; ks++) {
        bf16x8 a = *(const bf16x8*)(arow + ks * 32);
        acc0 = MFMA(a, *(const bf16x8*)(brow0 + ks * 32), acc0);
        acc1 = MFMA(a, *(const bf16x8*)(brow1 + ks * 32), acc1);
        acc2 = MFMA(a, *(const bf16x8*)(brow2 + ks * 32), acc2);
        acc3 = MFMA(a, *(const bf16x8*)(brow3 + ks * 32), acc3);
    }
    f32x4 accs[4] = {acc0, acc1, acc2, acc3};
    #pragma unroll
    for (int i = 0; i < 4; i++) {
        int o = obase + 4 * lg + i;
        float b = bo[o];
        #pragma unroll
        for (int ct = 0; ct < 4; ct++) {
            int p = pbase + ct * 16 + lr;
            out[o * 2304 + p] = accs[ct][i] + b;
        }
    }
}

extern "C" void kernel_launch(void* const* d_in, const int* in_sizes, int n_in,
                              void* d_out, int out_size, void* d_ws, size_t ws_size,
                              hipStream_t stream) {
    const float* x  = (const float*)d_in[0];
    const float* Wq = (const float*)d_in[1];
    const float* bq = (const float*)d_in[2];
    const float* Wk = (const float*)d_in[3];
    const float* bk = (const float*)d_in[4];
    const float* Wv = (const float*)d_in[5];
    const float* bv = (const float*)d_in[6];
    const float* Wo = (const float*)d_in[7];
    const float* bo = (const float*)d_in[8];

    char* ws = (char*)d_ws;
    short* Wall = (short*)(ws);                     // 1024*256*2 = 524288 B
    short* xt   = (short*)(ws + 524288);            // 2304*256*2 = 1179648 B
    short* Qf   = (short*)(ws + 1703936);           // 9216*64*2
    short* Kf   = (short*)(ws + 2883584);           // 9216*64*2
    short* Vt   = (short*)(ws + 4063232);           // 64*9216*2
    short* Of   = (short*)(ws + 5242880);           // 2304*256*2
    float* pm   = (float*)(ws + 6422528);           // 4*288*32*4 = 147456
    float* ps   = (float*)(ws + 6569984);           // 147456
    float* pacc = (float*)(ws + 6717440);           // 4*288*2048*4 = 9437184 (end ~16.2MB)
    float* out  = (float*)d_out;

    k_cast_w<<<1024, 256, 0, stream>>>(Wq, Wk, Wv, Wo, Wall);
    k_transpose_x<<<dim3(36, 4), 256, 0, stream>>>(x, xt);
    k_gemm_qkv<<<dim3(12, 36), 256, 0, stream>>>(Wall, xt, bq, bk, bv, Qf, Kf, Vt);
    k_attn<<<dim3(288, 4), 512, 0, stream>>>(Qf, Kf, Vt, pm, ps, pacc);
    k_attn_combine<<<288, 256, 0, stream>>>(pm, ps, pacc, Of);
    k_gemm_out<<<dim3(4, 36), 256, 0, stream>>>(Wall + 768 * 256, Of, bo, out);
}